// Round 1
// baseline (712.416 us; speedup 1.0000x reference)
//
#include <hip/hip_runtime.h>

// Downsample2d: depthwise 4x4 blur (separable taps 1/8,3/8,3/8,1/8),
// stride 2, reflect pad 1.
// x: (8,256,256,256) fp32 -> out: (8,256,128,128) fp32.
// HBM floor: ~544 MiB read (incl. strip overlap) + 128 MiB write ~= 110 us @ 6.3 TB/s.
//
// R2: horizontal blur during staging.
//   - stage phase: float4 row loads; H-blur computed in registers using two
//     __shfl for cross-lane taps (reflect handled at lanes 0/63); only the
//     128 H-values per row go to LDS -> 17 KiB/block (was 34 KiB).
//   - 8 blocks/CU (32/32 waves) via __launch_bounds__(256,8) -> 2x occupancy.
//   - compute phase: vertical blur only; 18 stride-1 ds_read_b32/thread
//     (2 lanes/bank = conflict-free) instead of 72 conflicted reads.

#define K0 0.125f
#define K1 0.375f

__global__ __launch_bounds__(256, 8) void downsample2d_kernel(
    const float* __restrict__ x, float* __restrict__ out)
{
    __shared__ float ldsH[34 * 128];          // 34 input rows x 128 H-values

    const int tid   = threadIdx.x;
    const int strip = blockIdx.x & 7;         // 8 strips of 16 output rows
    const int plane = blockIdx.x >> 3;        // b*C + c, 0..2047
    const int oh0   = strip * 16;
    const int ir0   = 2 * oh0 - 1;            // first input row of the strip

    const float* xp = x + (size_t)plane * (256 * 256);

    const int lane = tid & 63;
    const int wave = tid >> 6;

    // ---- stage: one wave loads one full input row (64 lanes x float4),
    //      computes 2 H-values per lane, writes float2 to LDS ----
    #pragma unroll
    for (int i = 0; i < 9; ++i) {
        int r = wave + 4 * i;                 // wave-uniform row index
        if (r < 34) {
            int gr = ir0 + r;
            gr = (gr < 0) ? 1 : ((gr > 255) ? 254 : gr);   // reflect rows
            float4 v = *(const float4*)(xp + gr * 256 + (lane << 2));
            float xm1 = __shfl_up(v.w, 1);    // col 4*lane - 1
            float xp4 = __shfl_down(v.x, 1);  // col 4*lane + 4
            if (lane == 0)  xm1 = v.y;        // reflect col -1  -> 1
            if (lane == 63) xp4 = v.z;        // reflect col 256 -> 254
            // H for output cols 2*lane, 2*lane+1
            float h0 = K0 * xm1 + K1 * v.x + K1 * v.y + K0 * v.z;
            float h1 = K0 * v.y + K1 * v.z + K1 * v.w + K0 * xp4;
            *(float2*)(&ldsH[r * 128 + (lane << 1)]) = make_float2(h0, h1);
        }
    }
    __syncthreads();

    // ---- compute: thread = one output column, 8 output rows (vertical blur) ----
    const int ow   = tid & 127;
    const int half = tid >> 7;                // 0: rows 0..7, 1: rows 8..15
    const float* L = ldsH + (half << 4) * 128 + ow;   // local H-row 0 or 16

    float* op = out + (size_t)plane * (128 * 128)
                    + (size_t)(oh0 + (half << 3)) * 128 + ow;

    float h0 = L[0];
    float h1 = L[128];
    #pragma unroll
    for (int l = 0; l < 8; ++l) {
        float h2 = L[(2 * l + 2) * 128];
        float h3 = L[(2 * l + 3) * 128];
        op[l * 128] = K0 * h0 + K1 * h1 + K1 * h2 + K0 * h3;
        h0 = h2;
        h1 = h3;
    }
}

extern "C" void kernel_launch(void* const* d_in, const int* in_sizes, int n_in,
                              void* d_out, int out_size, void* d_ws, size_t ws_size,
                              hipStream_t stream) {
    const float* x = (const float*)d_in[0];
    // d_in[1] is the 4x4 kernel == outer([1/8,3/8,3/8,1/8]) exactly; taps hardcoded.
    float* out = (float*)d_out;

    const int planes = 8 * 256;               // B*C
    const int blocks = planes * 8;            // 8 strips per plane
    downsample2d_kernel<<<blocks, 256, 0, stream>>>(x, out);
}